// Round 7
// baseline (131.482 us; speedup 1.0000x reference)
//
#include <hip/hip_runtime.h>

#define IMH 512
#define IMW 512
#define TW 16
#define TH 8
#define HW_ (TW + 2)          // 18
#define HH_ (TH + 2)          // 10
#define NHALO (HW_ * HH_)     // 180
#define NPIX (TW * TH)        // 128 interior pixels per block
#define ROWQ 8                // 8 quads (32 floats: 30 ch + 2 pad) per halo pixel

typedef float f4 __attribute__((ext_vector_type(4)));
typedef float f4a __attribute__((ext_vector_type(4), aligned(4)));
typedef float f2a __attribute__((ext_vector_type(2), aligned(4)));

// R7 = R6 (2 threads/px, clean registers) + XOR-swizzled b128 LDS layout.
// R6's wall: ~800 scalar-LDS wave-instrs/block (~15us/CU of LDS-unit issue).
// Rows are now 8 quads of 16B; quad q of row r lives at slot (q ^ (r&7)) so
// stride-128B b128 accesses are bank-conflict-free (16 consecutive lanes
// cover all 8 quad slots exactly twice = 2-way = free). Stage A: 8
// ds_write_b128 instead of 30 b32. Stage B: per tap, half 0 loads 4 quads
// (ch0-14), half 1 loads 6 (ch0-2,15-29), all groups fed from registers —
// ~3x fewer LDS instructions. All register arrays static-indexed.
__global__ __launch_bounds__(256, 4)
void hmm_fused(const float* __restrict__ obs,
               const float* __restrict__ P,      // (S,O) indexed P[o*3+s] per einsum 'os,hwo->hws'
               const float* __restrict__ u_k,
               const float* __restrict__ w_k,    // (H,W,S,1,S,O) -> pix*27 + s*9 + i*3 + j
               const float* __restrict__ conv_w, // (S_out,S_in,3,3)
               const float* __restrict__ conv_b, // (S,)
               float* __restrict__ out) {        // [0, 512*512*3): u_kp1 ; rest: w_kp1_O
    __shared__ f4 lds4[NHALO * ROWQ];            // 23,040 B
    float* lds = (float*)lds4;                   // alias for output staging

    const int tid = threadIdx.x;
    const int w0 = blockIdx.x * TW;
    const int h0 = blockIdx.y * TH;

    // P into registers (wave-uniform -> SGPRs)
    float Pm[9];
#pragma unroll
    for (int i = 0; i < 9; ++i) Pm[i] = P[i];

    // ---------- Stage A: halo pixels -> Z (ch 0..2) and w_pre (ch 3..29) in LDS
    if (tid < NHALO) {
        const int p = tid;
        const int hh = h0 + p / HW_ - 1;
        const int ww = w0 + p % HW_ - 1;
        const int sw = p & 7;
        f4* row4 = &lds4[p * ROWQ];
        if (hh < 0 || hh >= IMH || ww < 0 || ww >= IMW) {
            const f4 z4 = {0.0f, 0.0f, 0.0f, 0.0f};
#pragma unroll
            for (int q = 0; q < 8; ++q) row4[q ^ sw] = z4;   // SAME zero padding
        } else {
            const int pix = hh * IMW + ww;

            const f2a o01 = *(const f2a*)(obs + pix * 3);
            const float o2 = obs[pix * 3 + 2];
            const f2a u01 = *(const f2a*)(u_k + pix * 3);
            const float u2 = u_k[pix * 3 + 2];
            const float ov[3] = {o01.x, o01.y, o2};
            const float us[3] = {u01.x, u01.y, u2};

            // w_k slice: 27 floats as 6x float4 + float2 + float
            const float* wkp = &w_k[(size_t)pix * 27];
            float wreg[27];
            {
                const f4a* v4 = (const f4a*)wkp;
                const f4a a0 = v4[0], a1 = v4[1], a2 = v4[2], a3 = v4[3], a4 = v4[4], a5 = v4[5];
                const f2a a6 = *(const f2a*)(wkp + 24);
                const float a7 = wkp[26];
                wreg[0] = a0.x;  wreg[1] = a0.y;  wreg[2] = a0.z;  wreg[3] = a0.w;
                wreg[4] = a1.x;  wreg[5] = a1.y;  wreg[6] = a1.z;  wreg[7] = a1.w;
                wreg[8] = a2.x;  wreg[9] = a2.y;  wreg[10] = a2.z; wreg[11] = a2.w;
                wreg[12] = a3.x; wreg[13] = a3.y; wreg[14] = a3.z; wreg[15] = a3.w;
                wreg[16] = a4.x; wreg[17] = a4.y; wreg[18] = a4.z; wreg[19] = a4.w;
                wreg[20] = a5.x; wreg[21] = a5.y; wreg[22] = a5.z; wreg[23] = a5.w;
                wreg[24] = a6.x; wreg[25] = a6.y; wreg[26] = a7;
            }

            float b[3], Bu[3], bu = 0.0f;
#pragma unroll
            for (int s = 0; s < 3; ++s) {
                b[s] = Pm[0 * 3 + s] * ov[0] + Pm[1 * 3 + s] * ov[1] + Pm[2 * 3 + s] * ov[2];
                Bu[s] = b[s] * us[s];
                bu += Bu[s];
            }
            const float inv_bu = 1.0f / bu;
            float va[32];
            float Z[3];
#pragma unroll
            for (int s = 0; s < 3; ++s) { Z[s] = Bu[s] * inv_bu; va[s] = Z[s]; }

#pragma unroll
            for (int i = 0; i < 3; ++i) {
#pragma unroll
                for (int j = 0; j < 3; ++j) {
                    const int ij = i * 3 + j;
                    float du[3], sdu = 0.0f;
#pragma unroll
                    for (int s = 0; s < 3; ++s) {
                        float d = b[s] * wreg[s * 9 + ij];
                        if (s == j) d += ov[i] * us[s];
                        du[s] = d;
                        sdu += d;
                    }
#pragma unroll
                    for (int s = 0; s < 3; ++s)
                        va[(1 + ij) * 3 + s] = (du[s] - sdu * Z[s]) * inv_bu;
                }
            }
            va[30] = 0.0f; va[31] = 0.0f;

#pragma unroll
            for (int q = 0; q < 8; ++q)
                row4[q ^ sw] = (f4){va[4 * q + 0], va[4 * q + 1], va[4 * q + 2], va[4 * q + 3]};
        }
    }

    // conv weights/bias (wave-uniform loads -> SGPRs)
    float cw[81];
#pragma unroll
    for (int i = 0; i < 81; ++i) cw[i] = conv_w[i];
    const float cb0 = conv_b[0], cb1 = conv_b[1], cb2 = conv_b[2];

    __syncthreads();

    // ---------- Stage B: 2 threads per interior pixel (wave-uniform halves)
    const int half = tid >> 7;        // waves 0,1 -> half 0 ; waves 2,3 -> half 1
    const int pxl = tid & 127;
    const int tx = pxl & 15, ty = pxl >> 4;
    const int hp = (ty + 1) * HW_ + (tx + 1);
    const int pix = (h0 + ty) * IMW + (w0 + tx);

    // 9 FMAs of one conv group at tap T (cw[s*27+si*9+T] are SGPR-uniform)
#define ACC3(A0, A1, A2, V0, V1, V2, T)                                   \
    A0 += cw[0 + (T)] * (V0) + cw[9 + (T)] * (V1) + cw[18 + (T)] * (V2);  \
    A1 += cw[27 + (T)] * (V0) + cw[36 + (T)] * (V1) + cw[45 + (T)] * (V2);\
    A2 += cw[54 + (T)] * (V0) + cw[63 + (T)] * (V1) + cw[72 + (T)] * (V2);

    float y0 = cb0, y1 = cb1, y2 = cb2;                 // group 0
    float A10 = 0, A11 = 0, A12 = 0, A20 = 0, A21 = 0, A22 = 0;
    float A30 = 0, A31 = 0, A32 = 0, A40 = 0, A41 = 0, A42 = 0;
    float A50 = 0, A51 = 0, A52 = 0;                    // only half 1 uses A5x

    if (half == 0) {
        // groups 0..4  <- quads 0..3 per tap
#pragma unroll
        for (int ky = 0; ky < 3; ++ky) {
#pragma unroll
            for (int kx = 0; kx < 3; ++kx) {
                const int nbr = hp + (ky - 1) * HW_ + (kx - 1);
                const int sw = nbr & 7;
                const f4* base = &lds4[nbr * ROWQ];
                const f4 q0 = base[0 ^ sw], q1 = base[1 ^ sw];
                const f4 q2 = base[2 ^ sw], q3 = base[3 ^ sw];
                const int T = ky * 3 + kx;
                ACC3(y0,  y1,  y2,  q0.x, q0.y, q0.z, T)   // g0: ch 0..2
                ACC3(A10, A11, A12, q0.w, q1.x, q1.y, T)   // g1: ch 3..5
                ACC3(A20, A21, A22, q1.z, q1.w, q2.x, T)   // g2: ch 6..8
                ACC3(A30, A31, A32, q2.y, q2.z, q2.w, T)   // g3: ch 9..11
                ACC3(A40, A41, A42, q3.x, q3.y, q3.z, T)   // g4: ch 12..14
            }
        }
    } else {
        // groups 0, 5..9  <- quads 0, 3..7 per tap
#pragma unroll
        for (int ky = 0; ky < 3; ++ky) {
#pragma unroll
            for (int kx = 0; kx < 3; ++kx) {
                const int nbr = hp + (ky - 1) * HW_ + (kx - 1);
                const int sw = nbr & 7;
                const f4* base = &lds4[nbr * ROWQ];
                const f4 q0 = base[0 ^ sw], q3 = base[3 ^ sw], q4 = base[4 ^ sw];
                const f4 q5 = base[5 ^ sw], q6 = base[6 ^ sw], q7 = base[7 ^ sw];
                const int T = ky * 3 + kx;
                ACC3(y0,  y1,  y2,  q0.x, q0.y, q0.z, T)   // g0: ch 0..2
                ACC3(A10, A11, A12, q3.w, q4.x, q4.y, T)   // g5: ch 15..17
                ACC3(A20, A21, A22, q4.z, q4.w, q5.x, T)   // g6: ch 18..20
                ACC3(A30, A31, A32, q5.y, q5.z, q5.w, T)   // g7: ch 21..23
                ACC3(A40, A41, A42, q6.x, q6.y, q6.z, T)   // g8: ch 24..26
                ACC3(A50, A51, A52, q6.w, q7.x, q7.y, T)   // g9: ch 27..29
            }
        }
    }
#undef ACC3

    // softmax over states (group 0)
    const float m = fmaxf(y0, fmaxf(y1, y2));
    const float e0 = __expf(y0 - m), e1 = __expf(y1 - m), e2 = __expf(y2 - m);
    const float inv = 1.0f / (e0 + e1 + e2);
    const float p0 = e0 * inv, p1 = e1 * inv, p2 = e2 * inv;
    if (half == 0) { out[pix * 3 + 0] = p0; out[pix * 3 + 1] = p1; out[pix * 3 + 2] = p2; }

    // softmax JVP: w = p*(a - <p,a>), per group
    float wA[15];
#define JVP(K, A0, A1, A2)                        \
    {                                             \
        const float dot_ = p0 * (A0) + p1 * (A1) + p2 * (A2); \
        wA[(K) * 3 + 0] = p0 * ((A0) - dot_);     \
        wA[(K) * 3 + 1] = p1 * ((A1) - dot_);     \
        wA[(K) * 3 + 2] = p2 * ((A2) - dot_);     \
    }
    JVP(0, A10, A11, A12)
    JVP(1, A20, A21, A22)
    JVP(2, A30, A31, A32)
    JVP(3, A40, A41, A42)
    JVP(4, A50, A51, A52)   // garbage for half 0; never stored
#undef JVP

    __syncthreads();   // all halo reads done; LDS can be reused

    // stage w-output in LDS (slot = pxl*27 + s*9 + ij); stride 27 -> 2/bank, free
    if (half == 0) {
#pragma unroll
        for (int k = 0; k < 4; ++k)
#pragma unroll
            for (int s = 0; s < 3; ++s) lds[pxl * 27 + s * 9 + k] = wA[k * 3 + s];
    } else {
#pragma unroll
        for (int k = 0; k < 5; ++k)
#pragma unroll
            for (int s = 0; s < 3; ++s) lds[pxl * 27 + s * 9 + (4 + k)] = wA[k * 3 + s];
    }
    __syncthreads();

    // drain: 128 px * 27 ch = 3456 floats = 864 float4; 108 f4 per tile row
    float* outw = out + IMH * IMW * 3;
    for (int idx = tid; idx < NPIX * 27 / 4; idx += 256) {
        const int r = idx / 108;
        const int rem = idx - r * 108;
        *(f4*)(&outw[(h0 + r) * (IMW * 27) + w0 * 27 + rem * 4]) =
            *(const f4*)(&lds[idx * 4]);
    }
}

extern "C" void kernel_launch(void* const* d_in, const int* in_sizes, int n_in,
                              void* d_out, int out_size, void* d_ws, size_t ws_size,
                              hipStream_t stream) {
    const float* obs    = (const float*)d_in[0];
    const float* P      = (const float*)d_in[1];
    const float* u_k    = (const float*)d_in[2];
    const float* w_k    = (const float*)d_in[3];
    const float* conv_w = (const float*)d_in[4];
    const float* conv_b = (const float*)d_in[5];
    float* out = (float*)d_out;

    dim3 grid(IMW / TW, IMH / TH);   // (32, 64) = 2048 blocks
    hmm_fused<<<grid, 256, 0, stream>>>(obs, P, u_k, w_k, conv_w, conv_b, out);
}

// Round 8
// 105.579 us; speedup vs baseline: 1.2453x; 1.2453x over previous
//
#include <hip/hip_runtime.h>

#define IMH 512
#define IMW 512
#define TW 16
#define TH 8
#define HW_ (TW + 2)          // 18
#define HH_ (TH + 2)          // 10
#define NHALO (HW_ * HH_)     // 180
#define NPIX (TW * TH)        // 128 interior pixels per block
#define ROW 31                // padded floats per halo pixel (30 ch + 1 pad; gcd(31,32)=1)

typedef float f4 __attribute__((ext_vector_type(4)));
typedef float f4a __attribute__((ext_vector_type(4), aligned(4)));
typedef float f2a __attribute__((ext_vector_type(2), aligned(4)));

// R8 = R6 base (proven best: 2-phase, ROW=31 scalar LDS, clean registers) with
// stage B restructured as row-walking partial-sum conv:
//   B0: 128 thr (1/px): g0 conv + softmax -> u store + p into f4 aux (1 b128 write).
//   B1: 144 thr (16 cols x 9 JVP groups): walk the 10 halo rows once; per row
//       read 9 values, scatter into 3 rotating pending-output accumulators
//       (ky=0/1/2). Reads: 27 -> ~11.25 per px per group; g0 computed once;
//       p via one broadcast ds_read_b128; JVP stores direct to global (staging
//       + drain removed). ~2x fewer LDS instrs, only ~40 live VGPRs (R2/R5/R7
//       lesson: >50 live floats = backend spills).
// FMA order per accumulator preserved (ky 0,1,2 chronological; kx/ch identical).
__global__ __launch_bounds__(256, 4)
void hmm_fused(const float* __restrict__ obs,
               const float* __restrict__ P,      // (S,O) indexed P[o*3+s] per einsum 'os,hwo->hws'
               const float* __restrict__ u_k,
               const float* __restrict__ w_k,    // (H,W,S,1,S,O) -> pix*27 + s*9 + i*3 + j
               const float* __restrict__ conv_w, // (S_out,S_in,3,3)
               const float* __restrict__ conv_b, // (S,)
               float* __restrict__ out) {        // [0, 512*512*3): u_kp1 ; rest: w_kp1_O
    __shared__ __align__(16) float lds[NHALO * ROW];   // 22,320 B
    __shared__ f4 p_aux4[NPIX];                        // 2,048 B (p0,p1,p2,pad)

    const int tid = threadIdx.x;
    const int w0 = blockIdx.x * TW;
    const int h0 = blockIdx.y * TH;

    // P into registers (wave-uniform -> SGPRs)
    float Pm[9];
#pragma unroll
    for (int i = 0; i < 9; ++i) Pm[i] = P[i];

    // ---------- Stage A: halo pixels -> Z (ch 0..2) and w_pre (ch 3..29) in LDS
    if (tid < NHALO) {
        const int p = tid;
        const int hh = h0 + p / HW_ - 1;
        const int ww = w0 + p % HW_ - 1;
        float* row = &lds[p * ROW];
        if (hh < 0 || hh >= IMH || ww < 0 || ww >= IMW) {
#pragma unroll
            for (int c = 0; c < 30; ++c) row[c] = 0.0f;   // SAME zero padding
        } else {
            const int pix = hh * IMW + ww;

            const f2a o01 = *(const f2a*)(obs + pix * 3);
            const float o2 = obs[pix * 3 + 2];
            const f2a u01 = *(const f2a*)(u_k + pix * 3);
            const float u2 = u_k[pix * 3 + 2];
            const float ov[3] = {o01.x, o01.y, o2};
            const float us[3] = {u01.x, u01.y, u2};

            // w_k slice: 27 floats as 6x float4 + float2 + float
            const float* wkp = &w_k[(size_t)pix * 27];
            float wreg[27];
            {
                const f4a* v4 = (const f4a*)wkp;
                const f4a a0 = v4[0], a1 = v4[1], a2 = v4[2], a3 = v4[3], a4 = v4[4], a5 = v4[5];
                const f2a a6 = *(const f2a*)(wkp + 24);
                const float a7 = wkp[26];
                wreg[0] = a0.x;  wreg[1] = a0.y;  wreg[2] = a0.z;  wreg[3] = a0.w;
                wreg[4] = a1.x;  wreg[5] = a1.y;  wreg[6] = a1.z;  wreg[7] = a1.w;
                wreg[8] = a2.x;  wreg[9] = a2.y;  wreg[10] = a2.z; wreg[11] = a2.w;
                wreg[12] = a3.x; wreg[13] = a3.y; wreg[14] = a3.z; wreg[15] = a3.w;
                wreg[16] = a4.x; wreg[17] = a4.y; wreg[18] = a4.z; wreg[19] = a4.w;
                wreg[20] = a5.x; wreg[21] = a5.y; wreg[22] = a5.z; wreg[23] = a5.w;
                wreg[24] = a6.x; wreg[25] = a6.y; wreg[26] = a7;
            }

            float b[3], Bu[3], bu = 0.0f;
#pragma unroll
            for (int s = 0; s < 3; ++s) {
                b[s] = Pm[0 * 3 + s] * ov[0] + Pm[1 * 3 + s] * ov[1] + Pm[2 * 3 + s] * ov[2];
                Bu[s] = b[s] * us[s];
                bu += Bu[s];
            }
            const float inv_bu = 1.0f / bu;
            float Z[3];
#pragma unroll
            for (int s = 0; s < 3; ++s) { Z[s] = Bu[s] * inv_bu; row[s] = Z[s]; }

#pragma unroll
            for (int i = 0; i < 3; ++i) {
#pragma unroll
                for (int j = 0; j < 3; ++j) {
                    const int ij = i * 3 + j;
                    float du[3], sdu = 0.0f;
#pragma unroll
                    for (int s = 0; s < 3; ++s) {
                        float d = b[s] * wreg[s * 9 + ij];
                        if (s == j) d += ov[i] * us[s];
                        du[s] = d;
                        sdu += d;
                    }
#pragma unroll
                    for (int s = 0; s < 3; ++s)
                        row[(1 + ij) * 3 + s] = (du[s] - sdu * Z[s]) * inv_bu;
                }
            }
        }
    }

    // conv weights/bias (wave-uniform loads -> SGPRs). cw[s*27 + c*9 + ky*3 + kx]
    float cw[81];
#pragma unroll
    for (int i = 0; i < 81; ++i) cw[i] = conv_w[i];
    const float cb0 = conv_b[0], cb1 = conv_b[1], cb2 = conv_b[2];

    __syncthreads();

    float* outw = out + IMH * IMW * 3;

    // ---------- Stage B0: one thread per pixel: g0 conv + softmax -> u, p_aux
    if (tid < NPIX) {
        const int tx = tid & 15, ty = tid >> 4;
        const int hp = (ty + 1) * HW_ + (tx + 1);
        const int pix = (h0 + ty) * IMW + (w0 + tx);
        float y0 = cb0, y1 = cb1, y2 = cb2;
#pragma unroll
        for (int ky = 0; ky < 3; ++ky) {
#pragma unroll
            for (int kx = 0; kx < 3; ++kx) {
                const float* nb = &lds[(hp + (ky - 1) * HW_ + (kx - 1)) * ROW];
                const float v0 = nb[0], v1 = nb[1], v2 = nb[2];
                const int T = ky * 3 + kx;
                y0 += cw[0 + T] * v0 + cw[9 + T] * v1 + cw[18 + T] * v2;
                y1 += cw[27 + T] * v0 + cw[36 + T] * v1 + cw[45 + T] * v2;
                y2 += cw[54 + T] * v0 + cw[63 + T] * v1 + cw[72 + T] * v2;
            }
        }
        const float m = fmaxf(y0, fmaxf(y1, y2));
        const float e0 = __expf(y0 - m), e1 = __expf(y1 - m), e2 = __expf(y2 - m);
        const float inv = 1.0f / (e0 + e1 + e2);
        const float p0 = e0 * inv, p1 = e1 * inv, p2 = e2 * inv;
        out[pix * 3 + 0] = p0; out[pix * 3 + 1] = p1; out[pix * 3 + 2] = p2;
        p_aux4[tid] = (f4){p0, p1, p2, 0.0f};
    }

    __syncthreads();

    // ---------- Stage B1: 16 cols x 9 groups; walk 10 halo rows, 3 rotating
    // pending accumulators (ky=0 newest, ky=1 middle, ky=2 completes).
    if (tid < 144) {
        const int x = tid & 15;            // tile column
        const int g = (tid >> 4) + 1;      // JVP group 1..9
        const int ij = g - 1;
        const int gch = 3 * g;             // LDS channel offset of this group

        float a00, a01, a02;   // pending triplet A
        float b10, b11, b12;   // pending triplet B
        float c20, c21, c22;   // pending triplet C

#define ROWFMA(P0_, P1_, P2_, KY)                                                        \
        P0_ += cw[0 + (KY)*3 + 0] * v00 + cw[9 + (KY)*3 + 0] * v01 + cw[18 + (KY)*3 + 0] * v02; \
        P1_ += cw[27 + (KY)*3 + 0] * v00 + cw[36 + (KY)*3 + 0] * v01 + cw[45 + (KY)*3 + 0] * v02; \
        P2_ += cw[54 + (KY)*3 + 0] * v00 + cw[63 + (KY)*3 + 0] * v01 + cw[72 + (KY)*3 + 0] * v02; \
        P0_ += cw[0 + (KY)*3 + 1] * v10 + cw[9 + (KY)*3 + 1] * v11 + cw[18 + (KY)*3 + 1] * v12; \
        P1_ += cw[27 + (KY)*3 + 1] * v10 + cw[36 + (KY)*3 + 1] * v11 + cw[45 + (KY)*3 + 1] * v12; \
        P2_ += cw[54 + (KY)*3 + 1] * v10 + cw[63 + (KY)*3 + 1] * v11 + cw[72 + (KY)*3 + 1] * v12; \
        P0_ += cw[0 + (KY)*3 + 2] * v20 + cw[9 + (KY)*3 + 2] * v21 + cw[18 + (KY)*3 + 2] * v22; \
        P1_ += cw[27 + (KY)*3 + 2] * v20 + cw[36 + (KY)*3 + 2] * v21 + cw[45 + (KY)*3 + 2] * v22; \
        P2_ += cw[54 + (KY)*3 + 2] * v20 + cw[63 + (KY)*3 + 2] * v21 + cw[72 + (KY)*3 + 2] * v22;

#define FINISH(O, Q0, Q1, Q2) {                                                          \
        const f4 pv = p_aux4[(O) * 16 + x];                                              \
        const float dot_ = pv.x * (Q0) + pv.y * (Q1) + pv.z * (Q2);                      \
        float* wp = outw + ((size_t)((h0 + (O)) * IMW + (w0 + x))) * 27 + ij;            \
        wp[0]  = pv.x * ((Q0) - dot_);                                                   \
        wp[9]  = pv.y * ((Q1) - dot_);                                                   \
        wp[18] = pv.z * ((Q2) - dot_); }

        // DO_N/DO_M/DO_O are compile-time literals -> dead branches fold away.
#define STEP(R, N0,N1,N2, M0,M1,M2, O0,O1,O2, DO_N, DO_M, DO_O) {                        \
        const int rb = ((R) * HW_ + x) * ROW + gch;                                      \
        const float v00 = lds[rb + 0],  v01 = lds[rb + 1],  v02 = lds[rb + 2];           \
        const float v10 = lds[rb + 31], v11 = lds[rb + 32], v12 = lds[rb + 33];          \
        const float v20 = lds[rb + 62], v21 = lds[rb + 63], v22 = lds[rb + 64];          \
        if (DO_N) { N0 = 0.0f; N1 = 0.0f; N2 = 0.0f; ROWFMA(N0, N1, N2, 0) }             \
        if (DO_M) { ROWFMA(M0, M1, M2, 1) }                                              \
        if (DO_O) { ROWFMA(O0, O1, O2, 2) FINISH((R) - 2, O0, O1, O2) } }

        STEP(0, a00,a01,a02, b10,b11,b12, c20,c21,c22, true,  false, false)  // A:=out0
        STEP(1, b10,b11,b12, a00,a01,a02, c20,c21,c22, true,  true,  false)  // B:=out1; A ky1
        STEP(2, c20,c21,c22, b10,b11,b12, a00,a01,a02, true,  true,  true )  // C:=out2; B ky1; A fin(0)
        STEP(3, a00,a01,a02, c20,c21,c22, b10,b11,b12, true,  true,  true )  // A:=out3; C ky1; B fin(1)
        STEP(4, b10,b11,b12, a00,a01,a02, c20,c21,c22, true,  true,  true )  // B:=out4; A ky1; C fin(2)
        STEP(5, c20,c21,c22, b10,b11,b12, a00,a01,a02, true,  true,  true )  // C:=out5; B ky1; A fin(3)
        STEP(6, a00,a01,a02, c20,c21,c22, b10,b11,b12, true,  true,  true )  // A:=out6; C ky1; B fin(4)
        STEP(7, b10,b11,b12, a00,a01,a02, c20,c21,c22, true,  true,  true )  // B:=out7; A ky1; C fin(5)
        STEP(8, c20,c21,c22, b10,b11,b12, a00,a01,a02, false, true,  true )  // B ky1;  A fin(6)
        STEP(9, a00,a01,a02, c20,c21,c22, b10,b11,b12, false, false, true )  // B fin(7)

#undef STEP
#undef FINISH
#undef ROWFMA
    }
}

extern "C" void kernel_launch(void* const* d_in, const int* in_sizes, int n_in,
                              void* d_out, int out_size, void* d_ws, size_t ws_size,
                              hipStream_t stream) {
    const float* obs    = (const float*)d_in[0];
    const float* P      = (const float*)d_in[1];
    const float* u_k    = (const float*)d_in[2];
    const float* w_k    = (const float*)d_in[3];
    const float* conv_w = (const float*)d_in[4];
    const float* conv_b = (const float*)d_in[5];
    float* out = (float*)d_out;

    dim3 grid(IMW / TW, IMH / TH);   // (32, 64) = 2048 blocks
    hmm_fused<<<grid, 256, 0, stream>>>(obs, P, u_k, w_k, conv_w, conv_b, out);
}